// Round 6
// baseline (561.378 us; speedup 1.0000x reference)
//
#include <hip/hip_runtime.h>
#include <hip/hip_bf16.h>
#include <math.h>

// B=8 NC=64 N=128 DN=64 HS=HM=256 HMOD=64 MOD_IN=133 MOD_OUT=16512

typedef __bf16 bf16_t;
typedef __attribute__((ext_vector_type(8))) __bf16 bf16x8;
typedef __attribute__((ext_vector_type(4))) float f32x4;

__device__ __forceinline__ float fast_tanh(float x) {
  float e = __expf(2.0f * x);
  return 1.0f - 2.0f / (e + 1.0f);
}

__device__ __forceinline__ f32x4 mfma16(bf16x8 a, bf16x8 b, f32x4 c) {
  return __builtin_amdgcn_mfma_f32_16x16x32_bf16(a, b, c, 0, 0, 0);
}

// load 8 consecutive f32, convert to bf16x8 fragment
__device__ __forceinline__ bf16x8 ldcvt8(const float* p) {
  f32x4 a = *(const f32x4*)p;
  f32x4 b = *(const f32x4*)(p + 4);
  bf16x8 o;
#pragma unroll
  for (int u = 0; u < 4; ++u) { o[u] = (bf16_t)a[u]; o[u + 4] = (bf16_t)b[u]; }
  return o;
}

// ---- K0: convert the 4 shared MLP weight matrices to bf16 (229 KB) ----
// wbf layout: [0,49152) state_w1[256][192], [49152,65536) state_w2[64][256],
//             [65536,98304) msg_w1[256][128], [98304,114688) msg_w2[64][256]
__global__ __launch_bounds__(256) void k_convert(
    const float* __restrict__ sw1, const float* __restrict__ sw2,
    const float* __restrict__ mw1, const float* __restrict__ mw2,
    bf16_t* __restrict__ out) {
  int i = blockIdx.x * 256 + threadIdx.x;
  float v;
  if (i < 49152) v = sw1[i];
  else if (i < 65536) v = sw2[i - 49152];
  else if (i < 98304) v = mw1[i - 65536];
  else v = mw2[i - 98304];
  out[i] = (bf16_t)v;
}

// ---- K1: received + state MLP + msg MLP + modulator input + mod layer 1 ----
// One block = one (b,c). 8 waves x 16 rows/wave (512 thr). launch_bounds
// min-waves relaxed to 2 (VGPR cap 256, not 128) and hc loops fully
// unrolled: the per-wave serial load->mfma chain was the round-3/5
// bottleneck (all pipes idle); deep unroll + registers lets the scheduler
// batch the ~240 weight loads instead of consuming them one at a time.
__global__ __launch_bounds__(512, 2) void k_fused(
    const float* __restrict__ W, const float* __restrict__ msg,
    const float* __restrict__ h, const float* __restrict__ nid,
    const float* __restrict__ Haug, const float* __restrict__ injw,
    const float* __restrict__ injb, const bf16_t* __restrict__ wbf,
    const float* __restrict__ sb1, const float* __restrict__ sb2,
    const float* __restrict__ msb1, const float* __restrict__ msb2,
    const float* __restrict__ decay, const float* __restrict__ rdrift,
    const float* __restrict__ sml, const float* __restrict__ smf,
    const float* __restrict__ mw1, const float* __restrict__ mb1,
    float* __restrict__ out_h, float* __restrict__ out_m,
    float* __restrict__ hidden) {
  int bc = blockIdx.x, c = bc & 63, b = bc >> 6;
  __shared__ bf16_t Mt[64][136];    // msg^T [d][j]
  __shared__ bf16_t recs[128][72];  // received bf16 (wave-private rows)
  __shared__ bf16_t hs[128][72];    // hid1 / hid2 chunk (wave-private rows)
  __shared__ bf16_t hnew[128][72];  // h_new bf16 (wave-private rows)
  __shared__ float inj[128];
  __shared__ float hsum[8][64];     // per-wave h_new column sums
  __shared__ float msum[8][64];     // per-wave msg_new column sums
  __shared__ float wsum[8];         // per-wave sum|W|
  __shared__ float modin[133];
  int t = threadIdx.x;
  int wave = t >> 6, l = t & 63, lr = l & 15, kg = l >> 4;
  int r0 = wave * 16;

  // stage msg^T
  const float* Mp = msg + (size_t)bc * 8192;
  for (int s = 0; s < 4; ++s) {
    int e = (s * 512 + t) * 4;
    f32x4 v = *(const f32x4*)(Mp + e);
    int j = e >> 6, d = e & 63;
#pragma unroll
    for (int u = 0; u < 4; ++u) Mt[d + u][j] = (bf16_t)v[u];
  }
  if (t < 128) {  // inject row for input neurons
    const float* cell = Haug + (size_t)b * 4096 + c * 64;
    const float* iw = injw + (size_t)c * 8192 + t * 64;
    float a = injb[c * 128 + t];
    for (int k = 0; k < 64; k += 4) {
      f32x4 w4 = *(const f32x4*)(iw + k);
      a += cell[k] * w4[0] + cell[k + 1] * w4[1] + cell[k + 2] * w4[2] + cell[k + 3] * w4[3];
    }
    inj[t] = a;
  }

  // hoisted HBM loads: h / nid A-frags + decay (latency hides under phase R)
  const float* hp = h + (size_t)bc * 8192;
  const float* np2 = nid + (size_t)c * 8192;
  int arow = r0 + lr;
  bf16x8 aA[6];
  aA[0] = ldcvt8(hp + (size_t)arow * 64 + kg * 8);
  aA[1] = ldcvt8(hp + (size_t)arow * 64 + 32 + kg * 8);
  aA[4] = ldcvt8(np2 + (size_t)arow * 64 + kg * 8);
  aA[5] = ldcvt8(np2 + (size_t)arow * 64 + 32 + kg * 8);
  float dv0 = 0.f, dv1 = 0.f;
  if (wave == 7) {
    dv0 = decay[(size_t)bc * 128 + l];
    dv1 = decay[(size_t)bc * 128 + 64 + l];
  }
  __syncthreads();  // Mt + inj ready

  // ---- phase R: received = W @ msg; A from f32 W, |W| summed on the fly ----
  // asum kept as 4 independent partials so the fabs-add chain doesn't
  // serialize the W loads.
  const float* Wp = W + (size_t)bc * 16384;
  float asump[4] = {0.f, 0.f, 0.f, 0.f};
  f32x4 racc[4] = {};
#pragma unroll
  for (int ks = 0; ks < 4; ++ks) {
    int kof = ks * 32 + kg * 8;
    const float* p0 = Wp + (size_t)arow * 128 + kof;
    f32x4 x0 = *(const f32x4*)p0, x1 = *(const f32x4*)(p0 + 4);
    bf16x8 a0;
#pragma unroll
    for (int u = 0; u < 4; ++u) {
      a0[u] = (bf16_t)x0[u]; a0[u + 4] = (bf16_t)x1[u];
      asump[ks] += fabsf(x0[u]) + fabsf(x1[u]);
    }
#pragma unroll
    for (int ni = 0; ni < 4; ++ni) {
      bf16x8 bfr = *(const bf16x8*)&Mt[ni * 16 + lr][kof];
      racc[ni] = mfma16(a0, bfr, racc[ni]);
    }
  }
  float asum = (asump[0] + asump[1]) + (asump[2] + asump[3]);
#pragma unroll
  for (int ni = 0; ni < 4; ++ni)
#pragma unroll
    for (int r = 0; r < 4; ++r) {
      int row = r0 + kg * 4 + r, col = ni * 16 + lr;
      float v = racc[ni][r];
      if (row < 2) v += inj[row * 64 + col];
      recs[row][col] = (bf16_t)v;
    }

  // ---- phase 1: h_new = tanh(W2 @ tanh(W1 @ [h|rec|nid] + b1) + b2) ----
  aA[2] = *(const bf16x8*)&recs[arow][kg * 8];
  aA[3] = *(const bf16x8*)&recs[arow][32 + kg * 8];
  const bf16_t* w1b = wbf;
  const bf16_t* w2b = wbf + 49152;
  const bf16_t* w3b = wbf + 65536;
  const bf16_t* w4b = wbf + 98304;
  f32x4 acc2[4] = {};
#pragma unroll
  for (int hc = 0; hc < 4; ++hc) {
    f32x4 a1[4] = {};
#pragma unroll
    for (int ks = 0; ks < 6; ++ks) {
      int kof = ks * 32 + kg * 8;
#pragma unroll
      for (int ni = 0; ni < 4; ++ni) {
        bf16x8 bfr = *(const bf16x8*)(w1b + (size_t)(hc * 64 + ni * 16 + lr) * 192 + kof);
        a1[ni] = mfma16(aA[ks], bfr, a1[ni]);
      }
    }
#pragma unroll
    for (int ni = 0; ni < 4; ++ni) {
      float bias = sb1[hc * 64 + ni * 16 + lr];
#pragma unroll
      for (int r = 0; r < 4; ++r)
        hs[r0 + kg * 4 + r][ni * 16 + lr] = (bf16_t)fast_tanh(a1[ni][r] + bias);
    }
#pragma unroll
    for (int ks = 0; ks < 2; ++ks) {
      int kof = ks * 32 + kg * 8;
      bf16x8 af = *(const bf16x8*)&hs[arow][kof];
#pragma unroll
      for (int ni = 0; ni < 4; ++ni) {
        bf16x8 bfr = *(const bf16x8*)(w2b + (size_t)(ni * 16 + lr) * 256 + hc * 64 + kof);
        acc2[ni] = mfma16(af, bfr, acc2[ni]);
      }
    }
  }
  float* ohp = out_h + (size_t)bc * 8192;
  float hpart[4] = {0.f, 0.f, 0.f, 0.f};
#pragma unroll
  for (int ni = 0; ni < 4; ++ni) {
    float bias = sb2[ni * 16 + lr];
#pragma unroll
    for (int r = 0; r < 4; ++r) {
      int row = r0 + kg * 4 + r, col = ni * 16 + lr;
      float v = fast_tanh(acc2[ni][r] + bias);
      ohp[row * 64 + col] = v;
      hnew[row][col] = (bf16_t)v;
      hpart[ni] += v;
    }
  }
#pragma unroll
  for (int ni = 0; ni < 4; ++ni) {  // reduce over kg lanes -> wave col sum
    float s = hpart[ni];
    s += __shfl_xor(s, 16);
    s += __shfl_xor(s, 32);
    if (l < 16) hsum[wave][ni * 16 + l] = s;
  }

  // ---- phase 2: msg_new; k: 0-63 h_new (hnew), 64-127 received (recs) ----
  bf16x8 aB[4];
  aB[0] = *(const bf16x8*)&hnew[arow][kg * 8];
  aB[1] = *(const bf16x8*)&hnew[arow][32 + kg * 8];
  aB[2] = aA[2];
  aB[3] = aA[3];
  f32x4 acc3[4] = {};
#pragma unroll
  for (int hc = 0; hc < 4; ++hc) {
    f32x4 g3[4] = {};
#pragma unroll
    for (int ks = 0; ks < 4; ++ks) {
      int kof = ks * 32 + kg * 8;
#pragma unroll
      for (int ni = 0; ni < 4; ++ni) {
        bf16x8 bfr = *(const bf16x8*)(w3b + (size_t)(hc * 64 + ni * 16 + lr) * 128 + kof);
        g3[ni] = mfma16(aB[ks], bfr, g3[ni]);
      }
    }
#pragma unroll
    for (int ni = 0; ni < 4; ++ni) {
      float bias = msb1[hc * 64 + ni * 16 + lr];
#pragma unroll
      for (int r = 0; r < 4; ++r)
        hs[r0 + kg * 4 + r][ni * 16 + lr] = (bf16_t)fast_tanh(g3[ni][r] + bias);
    }
#pragma unroll
    for (int ks = 0; ks < 2; ++ks) {
      int kof = ks * 32 + kg * 8;
      bf16x8 af = *(const bf16x8*)&hs[arow][kof];
#pragma unroll
      for (int ni = 0; ni < 4; ++ni) {
        bf16x8 bfr = *(const bf16x8*)(w4b + (size_t)(ni * 16 + lr) * 256 + hc * 64 + kof);
        acc3[ni] = mfma16(af, bfr, acc3[ni]);
      }
    }
  }
  float* omp = out_m + (size_t)bc * 8192;
  float mpart[4] = {0.f, 0.f, 0.f, 0.f};
#pragma unroll
  for (int ni = 0; ni < 4; ++ni) {
    float bias = msb2[ni * 16 + lr];
#pragma unroll
    for (int r = 0; r < 4; ++r) {
      int row = r0 + kg * 4 + r, col = ni * 16 + lr;
      float v = fast_tanh(acc3[ni][r] + bias);
      omp[row * 64 + col] = v;
      mpart[ni] += v;
    }
  }
#pragma unroll
  for (int ni = 0; ni < 4; ++ni) {
    float s = mpart[ni];
    s += __shfl_xor(s, 16);
    s += __shfl_xor(s, 32);
    if (l < 16) msum[wave][ni * 16 + l] = s;
  }
  {  // |W| wave reduce
    float s = asum;
#pragma unroll
    for (int off = 32; off > 0; off >>= 1) s += __shfl_xor(s, off);
    if (l == 0) wsum[wave] = s;
  }
  if (wave == 7) {  // decay mean
    float s = dv0 + dv1;
#pragma unroll
    for (int off = 32; off > 0; off >>= 1) s += __shfl_xor(s, off);
    if (l == 0) modin[129] = s * (1.f / 128.f);
  }
  __syncthreads();  // hsum/msum/wsum/modin[129] ready

  if (t < 64) {
    float s = 0.f;
#pragma unroll
    for (int w = 0; w < 8; ++w) s += hsum[w][t];
    modin[t] = s * (1.f / 128.f);
  } else if (t < 128) {
    int d = t - 64;
    float s = 0.f;
#pragma unroll
    for (int w = 0; w < 8; ++w) s += msum[w][d];
    modin[64 + d] = s * (1.f / 128.f);
  } else if (t == 128) {
    float s = 0.f;
#pragma unroll
    for (int w = 0; w < 8; ++w) s += wsum[w];
    modin[128] = s * (1.f / 16384.f);
  } else if (t == 130) modin[130] = rdrift[bc];
  else if (t == 131) modin[131] = sml[b];
  else if (t == 132) modin[132] = smf[b];
  __syncthreads();  // modin ready

  if (t < 64) {  // modulator layer 1 (f32 exact)
    const float* w = mw1 + (size_t)c * 133 * 64;
    float a = mb1[c * 64 + t];
    for (int i = 0; i < 133; ++i) a += modin[i] * w[i * 64 + t];
    hidden[((size_t)(c * 64 + t)) * 8 + b] = fast_tanh(a);
  }
}

// ---- K2: mod_out = hidden @ mod_w2 + b2; W_new = W + dW; decay_new ----
__global__ __launch_bounds__(256) void k_apply(
    const float* __restrict__ hidden, const float* __restrict__ mw2,
    const float* __restrict__ mb2, const float* __restrict__ W,
    const float* __restrict__ decay, float* __restrict__ out_W,
    float* __restrict__ out_d) {
  int c = blockIdx.y, ch = blockIdx.x, t = threadIdx.x;
  __shared__ float hid[64][8];
  const float* hq = hidden + (size_t)c * 512;  // [h][b] for this c
  ((float*)hid)[t] = hq[t];
  ((float*)hid)[t + 256] = hq[t + 256];
  __syncthreads();
  int o = ch * 1024 + t * 4;
  if (o >= 16512) return;
  const float* w2 = mw2 + (size_t)c * 64 * 16512 + o;
  f32x4 bias = *(const f32x4*)(mb2 + (size_t)c * 16512 + o);
  f32x4 acc[8];
#pragma unroll
  for (int b = 0; b < 8; ++b) acc[b] = bias;
  for (int hh = 0; hh < 64; ++hh) {
    f32x4 wv = __builtin_nontemporal_load((const f32x4*)(w2 + (size_t)hh * 16512));
    f32x4 h0 = *(const f32x4*)&hid[hh][0];
    f32x4 h1 = *(const f32x4*)&hid[hh][4];
#pragma unroll
    for (int b = 0; b < 4; ++b) { acc[b] += h0[b] * wv; acc[b + 4] += h1[b] * wv; }
  }
  if (o < 16384) {
#pragma unroll
    for (int b = 0; b < 8; ++b) {
      size_t idx = (size_t)(b * 64 + c) * 16384 + o;
      f32x4 wv = *(const f32x4*)(W + idx);
      __builtin_nontemporal_store(wv + acc[b], (f32x4*)(out_W + idx));
    }
  } else {
    int i = o - 16384;
#pragma unroll
    for (int b = 0; b < 8; ++b) {
      size_t idx = (size_t)(b * 64 + c) * 128 + i;
      f32x4 dv = *(const f32x4*)(decay + idx);
      __builtin_nontemporal_store(dv + acc[b], (f32x4*)(out_d + idx));
    }
  }
}

extern "C" void kernel_launch(void* const* d_in, const int* in_sizes, int n_in,
                              void* d_out, int out_size, void* d_ws, size_t ws_size,
                              hipStream_t stream) {
  const float* h = (const float*)d_in[0];
  const float* msg = (const float*)d_in[1];
  const float* W = (const float*)d_in[2];
  const float* decay = (const float*)d_in[3];
  const float* rdrift = (const float*)d_in[4];
  const float* sml = (const float*)d_in[5];
  const float* smf = (const float*)d_in[6];
  const float* Haug = (const float*)d_in[7];
  const float* nid = (const float*)d_in[8];
  const float* sw1 = (const float*)d_in[9];
  const float* sb1 = (const float*)d_in[10];
  const float* sw2 = (const float*)d_in[11];
  const float* sb2 = (const float*)d_in[12];
  const float* mw1 = (const float*)d_in[13];
  const float* mb1 = (const float*)d_in[14];
  const float* mw2 = (const float*)d_in[15];
  const float* mb2 = (const float*)d_in[16];
  const float* injw = (const float*)d_in[17];
  const float* injb = (const float*)d_in[18];
  const float* modw1 = (const float*)d_in[19];
  const float* modb1 = (const float*)d_in[20];
  const float* modw2 = (const float*)d_in[21];
  const float* modb2 = (const float*)d_in[22];

  float* out = (float*)d_out;
  float* out_h = out;                // [8,64,128,64]
  float* out_m = out + 4194304;      // [8,64,128,64]
  float* out_W = out + 8388608;      // [8,64,128,128]
  float* out_d = out + 16777216;     // [8,64,128]

  char* wsb = (char*)d_ws;
  bf16_t* wbf = (bf16_t*)wsb;                  // 229 KB (pad to 256 KB)
  float* hidden = (float*)(wsb + 262144);      // 128 KB, [c][h][b]

  k_convert<<<448, 256, 0, stream>>>(sw1, sw2, mw1, mw2, wbf);
  k_fused<<<512, 512, 0, stream>>>(W, msg, h, nid, Haug, injw, injb, wbf,
                                   sb1, sb2, mb1, mb2, decay, rdrift, sml, smf,
                                   modw1, modb1, out_h, out_m, hidden);
  k_apply<<<dim3(17, 64), 256, 0, stream>>>(hidden, modw2, modb2, W, decay, out_W, out_d);
}

// Round 7
// 524.205 us; speedup vs baseline: 1.0709x; 1.0709x over previous
//
#include <hip/hip_runtime.h>
#include <hip/hip_bf16.h>
#include <math.h>

// B=8 NC=64 N=128 DN=64 HS=HM=256 HMOD=64 MOD_IN=133 MOD_OUT=16512

typedef __bf16 bf16_t;
typedef __attribute__((ext_vector_type(8))) __bf16 bf16x8;
typedef __attribute__((ext_vector_type(4))) float f32x4;

__device__ __forceinline__ float fast_tanh(float x) {
  float e = __expf(2.0f * x);
  return 1.0f - 2.0f / (e + 1.0f);
}

__device__ __forceinline__ f32x4 mfma16(bf16x8 a, bf16x8 b, f32x4 c) {
  return __builtin_amdgcn_mfma_f32_16x16x32_bf16(a, b, c, 0, 0, 0);
}

// load 8 consecutive f32, convert to bf16x8 fragment
__device__ __forceinline__ bf16x8 ldcvt8(const float* p) {
  f32x4 a = *(const f32x4*)p;
  f32x4 b = *(const f32x4*)(p + 4);
  bf16x8 o;
#pragma unroll
  for (int u = 0; u < 4; ++u) { o[u] = (bf16_t)a[u]; o[u + 4] = (bf16_t)b[u]; }
  return o;
}

// ---- K0: convert the 4 shared MLP weight matrices to bf16 (229 KB) ----
// wbf layout: [0,49152) state_w1[256][192], [49152,65536) state_w2[64][256],
//             [65536,98304) msg_w1[256][128], [98304,114688) msg_w2[64][256]
__global__ __launch_bounds__(256) void k_convert(
    const float* __restrict__ sw1, const float* __restrict__ sw2,
    const float* __restrict__ mw1, const float* __restrict__ mw2,
    bf16_t* __restrict__ out) {
  int i = blockIdx.x * 256 + threadIdx.x;
  float v;
  if (i < 49152) v = sw1[i];
  else if (i < 65536) v = sw2[i - 49152];
  else if (i < 98304) v = mw1[i - 65536];
  else v = mw2[i - 98304];
  out[i] = (bf16_t)v;
}

// ---- K1: received + state MLP + msg MLP + modulator input + mod layer 1 ----
// One block = one (b,c). 8 waves x 16 rows. GEMM1 B-operands (w1/w3, the
// 192-of-240 per-wave global loads) are now cooperatively STAGED into LDS:
// each wave issues ~20 staging loads instead of paying 240 serial L3
// latencies; B-frags come from pipelined ds_read_b128 (2-way bank alias,
// free). GEMM2 (w2/w4, 64 loads) stays global. inject and mod-layer-1 are
// wave-parallelized (serial depth 16->4 and 133->17).
__global__ __launch_bounds__(512, 2) void k_fused(
    const float* __restrict__ W, const float* __restrict__ msg,
    const float* __restrict__ h, const float* __restrict__ nid,
    const float* __restrict__ Haug, const float* __restrict__ injw,
    const float* __restrict__ injb, const bf16_t* __restrict__ wbf,
    const float* __restrict__ sb1, const float* __restrict__ sb2,
    const float* __restrict__ msb1, const float* __restrict__ msb2,
    const float* __restrict__ decay, const float* __restrict__ rdrift,
    const float* __restrict__ sml, const float* __restrict__ smf,
    const float* __restrict__ mw1, const float* __restrict__ mb1,
    float* __restrict__ out_h, float* __restrict__ out_m,
    float* __restrict__ hidden) {
  int bc = blockIdx.x, c = bc & 63, b = bc >> 6;
  __shared__ bf16_t Mt[64][136];    // msg^T [d][j]
  __shared__ bf16_t recs[128][72];  // received bf16 (wave-private rows)
  __shared__ bf16_t hs[128][72];    // hid1 / hid2 chunk (wave-private rows)
  __shared__ bf16_t hnew[128][72];  // h_new bf16 (wave-private rows)
  __shared__ float inj[128];
  __shared__ float hsum[8][64];     // per-wave h_new col sums; reused for mod-L1 partials
  __shared__ float msum[8][64];     // per-wave msg_new column sums
  __shared__ float wsum[8];         // per-wave sum|W|
  __shared__ float modin[133];
  // staged GEMM1 weight chunk: w1 chunks [64][192] at stride 200 (400 B row:
  // 16B-aligned, 100 dw = 4 mod 32 -> 2-way bank alias = free). Phase 2
  // reuses the region as [64][136] (272 B row, 68 dw = 4 mod 32).
  __shared__ __align__(16) bf16_t wstage[64 * 200];
  auto w1s = (bf16_t(*)[200])wstage;
  auto w3s = (bf16_t(*)[136])wstage;

  int t = threadIdx.x;
  int wave = t >> 6, l = t & 63, lr = l & 15, kg = l >> 4;
  int r0 = wave * 16;
  int arow = r0 + lr;

  // stage msg^T
  const float* Mp = msg + (size_t)bc * 8192;
  for (int s = 0; s < 4; ++s) {
    int e = (s * 512 + t) * 4;
    f32x4 v = *(const f32x4*)(Mp + e);
    int j = e >> 6, d = e & 63;
#pragma unroll
    for (int u = 0; u < 4; ++u) Mt[d + u][j] = (bf16_t)v[u];
  }
  {  // inject, wave-parallel: 4 threads per output row, depth 4
    int o = t >> 2, q = t & 3;
    const float* cell = Haug + (size_t)b * 4096 + c * 64 + q * 16;
    const float* iw = injw + (size_t)c * 8192 + o * 64 + q * 16;
    float a = 0.f;
#pragma unroll
    for (int k = 0; k < 16; k += 4) {
      f32x4 w4 = *(const f32x4*)(iw + k);
      f32x4 c4 = *(const f32x4*)(cell + k);
      a += c4[0] * w4[0] + c4[1] * w4[1] + c4[2] * w4[2] + c4[3] * w4[3];
    }
    a += __shfl_xor(a, 1);
    a += __shfl_xor(a, 2);
    if (q == 0) inj[o] = a + injb[c * 128 + o];
  }

  // hoisted HBM loads: W rows, h / nid A-frags, decay
  const float* Wp = W + (size_t)bc * 16384;
  f32x4 wx[8];
#pragma unroll
  for (int ks = 0; ks < 4; ++ks) {
    const float* p0 = Wp + (size_t)arow * 128 + ks * 32 + kg * 8;
    wx[ks * 2] = *(const f32x4*)p0;
    wx[ks * 2 + 1] = *(const f32x4*)(p0 + 4);
  }
  const float* hp = h + (size_t)bc * 8192;
  const float* np2 = nid + (size_t)c * 8192;
  bf16x8 aA[6];
  aA[0] = ldcvt8(hp + (size_t)arow * 64 + kg * 8);
  aA[1] = ldcvt8(hp + (size_t)arow * 64 + 32 + kg * 8);
  aA[4] = ldcvt8(np2 + (size_t)arow * 64 + kg * 8);
  aA[5] = ldcvt8(np2 + (size_t)arow * 64 + 32 + kg * 8);
  float dv0 = 0.f, dv1 = 0.f;
  if (wave == 7) {
    dv0 = decay[(size_t)bc * 128 + l];
    dv1 = decay[(size_t)bc * 128 + 64 + l];
  }
  __syncthreads();  // Mt + inj ready

  // ---- phase R: received = W @ msg (W from hoisted regs, |W| on the fly) ----
  float asump[4] = {0.f, 0.f, 0.f, 0.f};
  f32x4 racc[4] = {};
#pragma unroll
  for (int ks = 0; ks < 4; ++ks) {
    int kof = ks * 32 + kg * 8;
    f32x4 x0 = wx[ks * 2], x1 = wx[ks * 2 + 1];
    bf16x8 a0;
#pragma unroll
    for (int u = 0; u < 4; ++u) {
      a0[u] = (bf16_t)x0[u]; a0[u + 4] = (bf16_t)x1[u];
      asump[ks] += fabsf(x0[u]) + fabsf(x1[u]);
    }
#pragma unroll
    for (int ni = 0; ni < 4; ++ni) {
      bf16x8 bfr = *(const bf16x8*)&Mt[ni * 16 + lr][kof];
      racc[ni] = mfma16(a0, bfr, racc[ni]);
    }
  }
  float asum = (asump[0] + asump[1]) + (asump[2] + asump[3]);
#pragma unroll
  for (int ni = 0; ni < 4; ++ni)
#pragma unroll
    for (int r = 0; r < 4; ++r) {
      int row = r0 + kg * 4 + r, col = ni * 16 + lr;
      float v = racc[ni][r];
      if (row < 2) v += inj[row * 64 + col];
      recs[row][col] = (bf16_t)v;
    }

  // ---- phase 1: h_new = tanh(W2 @ tanh(W1 @ [h|rec|nid] + b1) + b2) ----
  aA[2] = *(const bf16x8*)&recs[arow][kg * 8];
  aA[3] = *(const bf16x8*)&recs[arow][32 + kg * 8];
  const bf16_t* w1b = wbf;
  const bf16_t* w2b = wbf + 49152;
  const bf16_t* w3b = wbf + 65536;
  const bf16_t* w4b = wbf + 98304;
  int shh = t >> 3;           // staging row for this thread
  int skk1 = (t & 7) * 24;    // w1 chunk: 8 groups of 24 cols
  int skk3 = (t & 7) * 16;    // w3 chunk: 8 groups of 16 cols
  f32x4 acc2[4] = {};
  for (int hc = 0; hc < 4; ++hc) {
    __syncthreads();  // prior chunk fully consumed
    {  // stage w1 chunk [64][192] -> w1s (3 bf16x8 per thread)
      const bf16_t* src = w1b + (size_t)(hc * 64 + shh) * 192 + skk1;
      *(bf16x8*)&w1s[shh][skk1] = *(const bf16x8*)src;
      *(bf16x8*)&w1s[shh][skk1 + 8] = *(const bf16x8*)(src + 8);
      *(bf16x8*)&w1s[shh][skk1 + 16] = *(const bf16x8*)(src + 16);
    }
    __syncthreads();  // chunk visible
    f32x4 a1[4] = {};
#pragma unroll
    for (int ks = 0; ks < 6; ++ks) {
      int kof = ks * 32 + kg * 8;
#pragma unroll
      for (int ni = 0; ni < 4; ++ni) {
        bf16x8 bfr = *(const bf16x8*)&w1s[ni * 16 + lr][kof];
        a1[ni] = mfma16(aA[ks], bfr, a1[ni]);
      }
    }
#pragma unroll
    for (int ni = 0; ni < 4; ++ni) {
      float bias = sb1[hc * 64 + ni * 16 + lr];
#pragma unroll
      for (int r = 0; r < 4; ++r)
        hs[r0 + kg * 4 + r][ni * 16 + lr] = (bf16_t)fast_tanh(a1[ni][r] + bias);
    }
#pragma unroll
    for (int ks = 0; ks < 2; ++ks) {
      int kof = ks * 32 + kg * 8;
      bf16x8 af = *(const bf16x8*)&hs[arow][kof];
#pragma unroll
      for (int ni = 0; ni < 4; ++ni) {
        bf16x8 bfr = *(const bf16x8*)(w2b + (size_t)(ni * 16 + lr) * 256 + hc * 64 + kof);
        acc2[ni] = mfma16(af, bfr, acc2[ni]);
      }
    }
  }
  float* ohp = out_h + (size_t)bc * 8192;
  float hpart[4] = {0.f, 0.f, 0.f, 0.f};
#pragma unroll
  for (int ni = 0; ni < 4; ++ni) {
    float bias = sb2[ni * 16 + lr];
#pragma unroll
    for (int r = 0; r < 4; ++r) {
      int row = r0 + kg * 4 + r, col = ni * 16 + lr;
      float v = fast_tanh(acc2[ni][r] + bias);
      ohp[row * 64 + col] = v;
      hnew[row][col] = (bf16_t)v;
      hpart[ni] += v;
    }
  }
#pragma unroll
  for (int ni = 0; ni < 4; ++ni) {  // reduce over kg lanes -> wave col sum
    float s = hpart[ni];
    s += __shfl_xor(s, 16);
    s += __shfl_xor(s, 32);
    if (l < 16) hsum[wave][ni * 16 + l] = s;
  }

  // ---- phase 2: msg_new; k: 0-63 h_new (hnew), 64-127 received (recs) ----
  bf16x8 aB[4];
  aB[0] = *(const bf16x8*)&hnew[arow][kg * 8];
  aB[1] = *(const bf16x8*)&hnew[arow][32 + kg * 8];
  aB[2] = aA[2];
  aB[3] = aA[3];
  f32x4 acc3[4] = {};
  for (int hc = 0; hc < 4; ++hc) {
    __syncthreads();  // prior chunk consumed (hc=0: phase-1 w1s reads done)
    {  // stage w3 chunk [64][128] -> w3s (2 bf16x8 per thread)
      const bf16_t* src = w3b + (size_t)(hc * 64 + shh) * 128 + skk3;
      *(bf16x8*)&w3s[shh][skk3] = *(const bf16x8*)src;
      *(bf16x8*)&w3s[shh][skk3 + 8] = *(const bf16x8*)(src + 8);
    }
    __syncthreads();
    f32x4 g3[4] = {};
#pragma unroll
    for (int ks = 0; ks < 4; ++ks) {
      int kof = ks * 32 + kg * 8;
#pragma unroll
      for (int ni = 0; ni < 4; ++ni) {
        bf16x8 bfr = *(const bf16x8*)&w3s[ni * 16 + lr][kof];
        g3[ni] = mfma16(aB[ks], bfr, g3[ni]);
      }
    }
#pragma unroll
    for (int ni = 0; ni < 4; ++ni) {
      float bias = msb1[hc * 64 + ni * 16 + lr];
#pragma unroll
      for (int r = 0; r < 4; ++r)
        hs[r0 + kg * 4 + r][ni * 16 + lr] = (bf16_t)fast_tanh(g3[ni][r] + bias);
    }
#pragma unroll
    for (int ks = 0; ks < 2; ++ks) {
      int kof = ks * 32 + kg * 8;
      bf16x8 af = *(const bf16x8*)&hs[arow][kof];
#pragma unroll
      for (int ni = 0; ni < 4; ++ni) {
        bf16x8 bfr = *(const bf16x8*)(w4b + (size_t)(ni * 16 + lr) * 256 + hc * 64 + kof);
        acc3[ni] = mfma16(af, bfr, acc3[ni]);
      }
    }
  }
  float* omp = out_m + (size_t)bc * 8192;
  float mpart[4] = {0.f, 0.f, 0.f, 0.f};
#pragma unroll
  for (int ni = 0; ni < 4; ++ni) {
    float bias = msb2[ni * 16 + lr];
#pragma unroll
    for (int r = 0; r < 4; ++r) {
      int row = r0 + kg * 4 + r, col = ni * 16 + lr;
      float v = fast_tanh(acc3[ni][r] + bias);
      omp[row * 64 + col] = v;
      mpart[ni] += v;
    }
  }
#pragma unroll
  for (int ni = 0; ni < 4; ++ni) {
    float s = mpart[ni];
    s += __shfl_xor(s, 16);
    s += __shfl_xor(s, 32);
    if (l < 16) msum[wave][ni * 16 + l] = s;
  }
  {  // |W| wave reduce
    float s = asum;
#pragma unroll
    for (int off = 32; off > 0; off >>= 1) s += __shfl_xor(s, off);
    if (l == 0) wsum[wave] = s;
  }
  if (wave == 7) {  // decay mean
    float s = dv0 + dv1;
#pragma unroll
    for (int off = 32; off > 0; off >>= 1) s += __shfl_xor(s, off);
    if (l == 0) modin[129] = s * (1.f / 128.f);
  }
  __syncthreads();  // hsum/msum/wsum/modin[129] ready

  if (t < 64) {
    float s = 0.f;
#pragma unroll
    for (int w = 0; w < 8; ++w) s += hsum[w][t];
    modin[t] = s * (1.f / 128.f);
  } else if (t < 128) {
    int d = t - 64;
    float s = 0.f;
#pragma unroll
    for (int w = 0; w < 8; ++w) s += msum[w][d];
    modin[64 + d] = s * (1.f / 128.f);
  } else if (t == 128) {
    float s = 0.f;
#pragma unroll
    for (int w = 0; w < 8; ++w) s += wsum[w];
    modin[128] = s * (1.f / 16384.f);
  } else if (t == 130) modin[130] = rdrift[bc];
  else if (t == 131) modin[131] = sml[b];
  else if (t == 132) modin[132] = smf[b];
  __syncthreads();  // modin ready

  {  // modulator layer 1, wave-parallel: wave g sums inputs [g*17, ...)
    const float* w = mw1 + (size_t)c * 133 * 64;
    int i0 = wave * 17, i1 = i0 + 17 > 133 ? 133 : i0 + 17;
    float p = 0.f;
    for (int i = i0; i < i1; ++i) p += modin[i] * w[i * 64 + l];
    hsum[wave][l] = p;  // hsum free for reuse after modin barrier
  }
  __syncthreads();
  if (t < 64) {
    float a = mb1[c * 64 + t];
#pragma unroll
    for (int g = 0; g < 8; ++g) a += hsum[g][t];
    hidden[((size_t)(c * 64 + t)) * 8 + b] = fast_tanh(a);
  }
}

// ---- K2: mod_out = hidden @ mod_w2 + b2; W_new = W + dW; decay_new ----
__global__ __launch_bounds__(256) void k_apply(
    const float* __restrict__ hidden, const float* __restrict__ mw2,
    const float* __restrict__ mb2, const float* __restrict__ W,
    const float* __restrict__ decay, float* __restrict__ out_W,
    float* __restrict__ out_d) {
  int c = blockIdx.y, ch = blockIdx.x, t = threadIdx.x;
  __shared__ float hid[64][8];
  const float* hq = hidden + (size_t)c * 512;  // [h][b] for this c
  ((float*)hid)[t] = hq[t];
  ((float*)hid)[t + 256] = hq[t + 256];
  __syncthreads();
  int o = ch * 1024 + t * 4;
  if (o >= 16512) return;
  const float* w2 = mw2 + (size_t)c * 64 * 16512 + o;
  f32x4 bias = *(const f32x4*)(mb2 + (size_t)c * 16512 + o);
  f32x4 acc[8];
#pragma unroll
  for (int b = 0; b < 8; ++b) acc[b] = bias;
  for (int hh = 0; hh < 64; ++hh) {
    f32x4 wv = __builtin_nontemporal_load((const f32x4*)(w2 + (size_t)hh * 16512));
    f32x4 h0 = *(const f32x4*)&hid[hh][0];
    f32x4 h1 = *(const f32x4*)&hid[hh][4];
#pragma unroll
    for (int b = 0; b < 4; ++b) { acc[b] += h0[b] * wv; acc[b + 4] += h1[b] * wv; }
  }
  if (o < 16384) {
#pragma unroll
    for (int b = 0; b < 8; ++b) {
      size_t idx = (size_t)(b * 64 + c) * 16384 + o;
      f32x4 wv = *(const f32x4*)(W + idx);
      __builtin_nontemporal_store(wv + acc[b], (f32x4*)(out_W + idx));
    }
  } else {
    int i = o - 16384;
#pragma unroll
    for (int b = 0; b < 8; ++b) {
      size_t idx = (size_t)(b * 64 + c) * 128 + i;
      f32x4 dv = *(const f32x4*)(decay + idx);
      __builtin_nontemporal_store(dv + acc[b], (f32x4*)(out_d + idx));
    }
  }
}

extern "C" void kernel_launch(void* const* d_in, const int* in_sizes, int n_in,
                              void* d_out, int out_size, void* d_ws, size_t ws_size,
                              hipStream_t stream) {
  const float* h = (const float*)d_in[0];
  const float* msg = (const float*)d_in[1];
  const float* W = (const float*)d_in[2];
  const float* decay = (const float*)d_in[3];
  const float* rdrift = (const float*)d_in[4];
  const float* sml = (const float*)d_in[5];
  const float* smf = (const float*)d_in[6];
  const float* Haug = (const float*)d_in[7];
  const float* nid = (const float*)d_in[8];
  const float* sw1 = (const float*)d_in[9];
  const float* sb1 = (const float*)d_in[10];
  const float* sw2 = (const float*)d_in[11];
  const float* sb2 = (const float*)d_in[12];
  const float* mw1 = (const float*)d_in[13];
  const float* mb1 = (const float*)d_in[14];
  const float* mw2 = (const float*)d_in[15];
  const float* mb2 = (const float*)d_in[16];
  const float* injw = (const float*)d_in[17];
  const float* injb = (const float*)d_in[18];
  const float* modw1 = (const float*)d_in[19];
  const float* modb1 = (const float*)d_in[20];
  const float* modw2 = (const float*)d_in[21];
  const float* modb2 = (const float*)d_in[22];

  float* out = (float*)d_out;
  float* out_h = out;                // [8,64,128,64]
  float* out_m = out + 4194304;      // [8,64,128,64]
  float* out_W = out + 8388608;      // [8,64,128,128]
  float* out_d = out + 16777216;     // [8,64,128]

  char* wsb = (char*)d_ws;
  bf16_t* wbf = (bf16_t*)wsb;                  // 229 KB (pad to 256 KB)
  float* hidden = (float*)(wsb + 262144);      // 128 KB, [c][h][b]

  k_convert<<<448, 256, 0, stream>>>(sw1, sw2, mw1, mw2, wbf);
  k_fused<<<512, 512, 0, stream>>>(W, msg, h, nid, Haug, injw, injb, wbf,
                                   sb1, sb2, mb1, mb2, decay, rdrift, sml, smf,
                                   modw1, modb1, out_h, out_m, hidden);
  k_apply<<<dim3(17, 64), 256, 0, stream>>>(hidden, modw2, modb2, W, decay, out_W, out_d);
}